// Round 3
// baseline (116.202 us; speedup 1.0000x reference)
//
#include <hip/hip_runtime.h>

#define N_SAMPLES 128
#define EPS 1e-10f

typedef float f4 __attribute__((ext_vector_type(4)));   // native vector: OK for nontemporal builtins

// One 64-lane wave handles TWO rays: lanes 0-31 -> ray 2w, lanes 32-63 -> ray 2w+1.
// Each lane owns 4 consecutive samples of its ray:
//   alpha: one float4 (16 B, 512 B contiguous per ray across 32 lanes)
//   rgb:   3 float4 (48 B per lane; lane's 12 floats start at channel 0)
// weights[s] = alpha[s] * prod_{j<s}(1 - alpha[j] + EPS)
__global__ __launch_bounds__(256) void VolumeRenderer_14336600834233_kernel(
    const f4* __restrict__ alpha4,
    const f4* __restrict__ rgb4,
    float* __restrict__ out,
    int n_rays)
{
    const int wavesPerBlock = blockDim.x >> 6;
    const int wave = blockIdx.x * wavesPerBlock + (threadIdx.x >> 6);
    const int lane = threadIdx.x & 63;
    const int g    = lane >> 5;     // which ray of the pair
    const int l    = lane & 31;     // lane within the 32-lane group
    const int ray  = wave * 2 + g;
    if (ray >= n_rays) return;

    // ---- alpha: 128 floats/ray = 32 float4; lane l takes samples 4l..4l+3 ----
    const f4 av = __builtin_nontemporal_load(&alpha4[(size_t)ray * 32 + l]);
    const float f0 = 1.0f - av.x + EPS;
    const float f1 = 1.0f - av.y + EPS;
    const float f2 = 1.0f - av.z + EPS;
    const float f3 = 1.0f - av.w + EPS;
    const float p  = (f0 * f1) * (f2 * f3);

    // ---- inclusive product-scan within each 32-lane group (5 steps) ----
    float incl = p;
    #pragma unroll
    for (int off = 1; off < 32; off <<= 1) {
        float v = __shfl_up(incl, off, 64);   // cross-group pulls discarded by predicate
        incl = (l >= off) ? incl * v : incl;
    }
    float excl = __shfl_up(incl, 1, 64);      // product of all samples before 4l
    if (l == 0) excl = 1.0f;

    // ---- per-sample weights (shift-by-1 transmittance) ----
    const float w0 = av.x * excl;
    const float t1 = excl * f0;
    const float w1 = av.y * t1;
    const float t2 = t1 * f1;
    const float w2 = av.z * t2;
    const float w3 = av.w * (t2 * f2);

    // ---- rgb: 384 floats/ray = 96 float4; lane l -> float4 indices 3l..3l+2 ----
    // x0 = [r0,g0,b0,r1]  x1 = [g1,b1,r2,g2]  x2 = [b2,r3,g3,b3]
    const size_t rb = (size_t)ray * 96 + (size_t)l * 3;
    const f4 x0 = __builtin_nontemporal_load(&rgb4[rb + 0]);
    const f4 x1 = __builtin_nontemporal_load(&rgb4[rb + 1]);
    const f4 x2 = __builtin_nontemporal_load(&rgb4[rb + 2]);

    float cr = fmaf(w0, x0.x, fmaf(w1, x0.w, fmaf(w2, x1.z, w3 * x2.y)));
    float cg = fmaf(w0, x0.y, fmaf(w1, x1.x, fmaf(w2, x1.w, w3 * x2.z)));
    float cb = fmaf(w0, x0.z, fmaf(w1, x1.y, fmaf(w2, x2.x, w3 * x2.w)));

    // ---- sum-reduce within each 32-lane group (5 shfl_xor steps) ----
    #pragma unroll
    for (int off = 16; off; off >>= 1) {
        cr += __shfl_xor(cr, off, 64);   // off<=16 never crosses the 32-lane half
        cg += __shfl_xor(cg, off, 64);
        cb += __shfl_xor(cb, off, 64);
    }

    if (l == 0) {
        float* o = out + (size_t)ray * 3;
        __builtin_nontemporal_store(cr, o + 0);
        __builtin_nontemporal_store(cg, o + 1);
        __builtin_nontemporal_store(cb, o + 2);
    }
}

extern "C" void kernel_launch(void* const* d_in, const int* in_sizes, int n_in,
                              void* d_out, int out_size, void* d_ws, size_t ws_size,
                              hipStream_t stream) {
    const f4* alpha4 = (const f4*)d_in[0];
    const f4* rgb4   = (const f4*)d_in[1];
    float* out = (float*)d_out;

    const int n_rays = in_sizes[0] / N_SAMPLES;   // 262144

    const int block = 256;                         // 4 waves -> 8 rays per block
    const int rays_per_block = (block / 64) * 2;
    const int grid = (n_rays + rays_per_block - 1) / rays_per_block;

    VolumeRenderer_14336600834233_kernel<<<grid, block, 0, stream>>>(
        alpha4, rgb4, out, n_rays);
}

// Round 4
// 95.084 us; speedup vs baseline: 1.2221x; 1.2221x over previous
//
#include <hip/hip_runtime.h>

#define N_SAMPLES 128
#define EPS 1e-10f

typedef float f4 __attribute__((ext_vector_type(4)));

// One 64-lane wave handles TWO rays: lanes 0-31 -> ray 2w, lanes 32-63 -> ray 2w+1.
// Each lane owns 4 consecutive samples of its ray:
//   alpha: one float4 (512 B contiguous per ray across 32 lanes)
//   rgb:   3 float4 (48 B per lane, full 1536 B ray block covered; L1 merges lines)
// weights[s] = alpha[s] * prod_{j<s}(1 - alpha[j] + EPS)
__global__ __launch_bounds__(256) void VolumeRenderer_14336600834233_kernel(
    const f4* __restrict__ alpha4,
    const f4* __restrict__ rgb4,
    float* __restrict__ out,
    int n_rays)
{
    const int wavesPerBlock = blockDim.x >> 6;
    const int wave = blockIdx.x * wavesPerBlock + (threadIdx.x >> 6);
    const int lane = threadIdx.x & 63;
    const int g    = lane >> 5;     // which ray of the pair
    const int l    = lane & 31;     // lane within the 32-lane group
    const int ray  = wave * 2 + g;
    if (ray >= n_rays) return;

    // ---- alpha: 128 floats/ray = 32 float4; lane l takes samples 4l..4l+3 ----
    const f4 av = alpha4[(size_t)ray * 32 + l];
    const float f0 = 1.0f - av.x + EPS;
    const float f1 = 1.0f - av.y + EPS;
    const float f2 = 1.0f - av.z + EPS;
    const float f3 = 1.0f - av.w + EPS;
    const float p  = (f0 * f1) * (f2 * f3);

    // ---- inclusive product-scan within each 32-lane group (5 steps) ----
    float incl = p;
    #pragma unroll
    for (int off = 1; off < 32; off <<= 1) {
        float v = __shfl_up(incl, off, 64);   // cross-group pulls discarded by predicate
        incl = (l >= off) ? incl * v : incl;
    }
    float excl = __shfl_up(incl, 1, 64);      // product of all samples before 4l
    if (l == 0) excl = 1.0f;

    // ---- per-sample weights (shift-by-1 transmittance) ----
    const float w0 = av.x * excl;
    const float t1 = excl * f0;
    const float w1 = av.y * t1;
    const float t2 = t1 * f1;
    const float w2 = av.z * t2;
    const float w3 = av.w * (t2 * f2);

    // ---- rgb: 384 floats/ray = 96 float4; lane l -> float4 indices 3l..3l+2 ----
    // x0 = [r0,g0,b0,r1]  x1 = [g1,b1,r2,g2]  x2 = [b2,r3,g3,b3]
    const size_t rb = (size_t)ray * 96 + (size_t)l * 3;
    const f4 x0 = rgb4[rb + 0];
    const f4 x1 = rgb4[rb + 1];
    const f4 x2 = rgb4[rb + 2];

    float cr = fmaf(w0, x0.x, fmaf(w1, x0.w, fmaf(w2, x1.z, w3 * x2.y)));
    float cg = fmaf(w0, x0.y, fmaf(w1, x1.x, fmaf(w2, x1.w, w3 * x2.z)));
    float cb = fmaf(w0, x0.z, fmaf(w1, x1.y, fmaf(w2, x2.x, w3 * x2.w)));

    // ---- sum-reduce within each 32-lane group (5 shfl_xor steps) ----
    #pragma unroll
    for (int off = 16; off; off >>= 1) {
        cr += __shfl_xor(cr, off, 64);   // off<=16 never crosses the 32-lane half
        cg += __shfl_xor(cg, off, 64);
        cb += __shfl_xor(cb, off, 64);
    }

    if (l == 0) {
        float* o = out + (size_t)ray * 3;
        o[0] = cr;
        o[1] = cg;
        o[2] = cb;
    }
}

extern "C" void kernel_launch(void* const* d_in, const int* in_sizes, int n_in,
                              void* d_out, int out_size, void* d_ws, size_t ws_size,
                              hipStream_t stream) {
    const f4* alpha4 = (const f4*)d_in[0];
    const f4* rgb4   = (const f4*)d_in[1];
    float* out = (float*)d_out;

    const int n_rays = in_sizes[0] / N_SAMPLES;   // 262144

    const int block = 256;                         // 4 waves -> 8 rays per block
    const int rays_per_block = (block / 64) * 2;
    const int grid = (n_rays + rays_per_block - 1) / rays_per_block;

    VolumeRenderer_14336600834233_kernel<<<grid, block, 0, stream>>>(
        alpha4, rgb4, out, n_rays);
}